// Round 5
// baseline (558.357 us; speedup 1.0000x reference)
//
#include <hip/hip_runtime.h>
#include <hip/hip_bf16.h>

typedef __hip_bfloat16 bf16;
typedef __bf16 bf16x8 __attribute__((ext_vector_type(8)));
typedef float f32x4 __attribute__((ext_vector_type(4)));
typedef unsigned short u16x4 __attribute__((ext_vector_type(4)));
typedef unsigned int u32x4 __attribute__((ext_vector_type(4)));
#define FDIM 64
#define KTOT 384
#define LDSK 392   // padded K-stride for W^T in LDS
#define SNIFF_THRESH 100
#define MAXNB 1024 // max node buckets (supports N <= 131072; here N=100K -> 782)
#define EBLK 4096  // edges per CSR-build block (4096 -> 391 WGs, >1 WG/CU)
#define KITER (EBLK / 256)

__device__ __forceinline__ float us2f(unsigned short u) {
  union { unsigned int i; float f; } v; v.i = ((unsigned int)u) << 16; return v.f;
}
__device__ __forceinline__ unsigned short f2bu(float v) {
  bf16 h = __float2bfloat16(v);
  return *(unsigned short*)&h;
}
__device__ __forceinline__ unsigned int pack2(float a, float b) {
  return (unsigned int)f2bu(a) | ((unsigned int)f2bu(b) << 16);
}
__device__ __forceinline__ float inv_sqrt_pos(float d) { return d > 0.f ? rsqrtf(d) : 0.f; }

// ---------- dtype sniffing & canonicalization ----------
__global__ __launch_bounds__(256)
void k_sniff(const unsigned short* __restrict__ xs, int n, int* __restrict__ cnt) {
  int local = 0;
  for (int i = blockIdx.x * 256 + threadIdx.x; i < n; i += 256 * 256)
    local += ((xs[i] & 0x7F80) == 0x7F80) ? 1 : 0;
  #pragma unroll
  for (int d = 32; d >= 1; d >>= 1) local += __shfl_down(local, d);
  __shared__ int sm[4];
  if ((threadIdx.x & 63) == 0) sm[threadIdx.x >> 6] = local;
  __syncthreads();
  if (threadIdx.x == 0) {
    int t = sm[0] + sm[1] + sm[2] + sm[3];
    if (t) atomicAdd(cnt, t);
  }
}

// Vectorized: 4 elements per thread. n4 = n/4.
__global__ __launch_bounds__(256)
void k_convert_x(const void* __restrict__ xin, bf16* __restrict__ xb,
                 const int* __restrict__ cnt, int n4) {
  int i = blockIdx.x * 256 + threadIdx.x;
  if (i >= n4) return;
  ushort4 o;
  if (*cnt > SNIFF_THRESH) {
    float4 v = ((const float4*)xin)[i];
    o.x = f2bu(v.x); o.y = f2bu(v.y); o.z = f2bu(v.z); o.w = f2bu(v.w);
  } else {
    o = ((const ushort4*)xin)[i];
  }
  ((ushort4*)xb)[i] = o;
}

// W^T-concat: wt[n*384 + si*64 + kk] = W_si[kk][n]; bsum[n] = sum_si b_si[n] (fp32)
__global__ void k_convert_w(const void* W0, const void* W1, const void* W2,
                            const void* W3, const void* W4, const void* W5,
                            const void* c0, const void* c1, const void* c2,
                            const void* c3, const void* c4, const void* c5,
                            bf16* __restrict__ wt, float* __restrict__ bsum,
                            const int* __restrict__ cnt) {
  int t = blockIdx.x * 256 + threadIdx.x;
  const void* Ws[6] = {W0, W1, W2, W3, W4, W5};
  const void* Bs[6] = {c0, c1, c2, c3, c4, c5};
  bool fp = (*cnt > SNIFF_THRESH);
  if (t < 6 * 4096) {
    int si = t >> 12, o = t & 4095;
    int kk = o >> 6, n = o & 63;
    float v = fp ? ((const float*)Ws[si])[o] : __bfloat162float(((const bf16*)Ws[si])[o]);
    wt[n * KTOT + si * 64 + kk] = __float2bfloat16(v);
  } else if (t < 6 * 4096 + 64) {
    int n = t - 6 * 4096;
    float s = 0.f;
    for (int si = 0; si < 6; si++)
      s += fp ? ((const float*)Bs[si])[n] : __bfloat162float(((const bf16*)Bs[si])[n]);
    bsum[n] = s;
  }
}

// ---------- CSR build via LDS counting sort (no global atomics) ----------
__global__ __launch_bounds__(256)
void k_hist(const int* __restrict__ row, const int* __restrict__ col,
            int* __restrict__ hist, int E, int NB, int NBLK) {
  __shared__ int hr[MAXNB], hc[MAXNB];
  for (int i = threadIdx.x; i < NB; i += 256) { hr[i] = 0; hc[i] = 0; }
  __syncthreads();
  int base = blockIdx.x * EBLK;
  for (int k = 0; k < KITER; k++) {
    int e = base + k * 256 + threadIdx.x;
    if (e < E) {
      int r = __builtin_nontemporal_load(&row[e]);
      int c = __builtin_nontemporal_load(&col[e]);
      atomicAdd(&hr[r >> 7], 1);
      atomicAdd(&hc[c >> 7], 1);
    }
  }
  __syncthreads();
  for (int i = threadIdx.x; i < NB; i += 256) {
    hist[(size_t)i * NBLK + blockIdx.x] = hr[i];
    hist[(size_t)(NB + i) * NBLK + blockIdx.x] = hc[i];
  }
}

__global__ void k_scan_block(const int* __restrict__ in, int* __restrict__ out,
                             int* __restrict__ part, int n) {
  __shared__ int sm[256];
  int tid = threadIdx.x;
  int i = blockIdx.x * 256 + tid;
  int v = (i < n) ? in[i] : 0;
  sm[tid] = v;
  __syncthreads();
  for (int d = 1; d < 256; d <<= 1) {
    int t = (tid >= d) ? sm[tid - d] : 0;
    __syncthreads();
    if (tid >= d) sm[tid] += t;
    __syncthreads();
  }
  if (i < n) out[i] = sm[tid] - v;
  if (tid == 255) part[blockIdx.x] = sm[255];
}

__global__ void k_scan_part(int* part, int nb) {
  __shared__ int sm[1024];
  int tid = threadIdx.x;
  int v = (tid < nb) ? part[tid] : 0;
  sm[tid] = v;
  __syncthreads();
  for (int d = 1; d < 1024; d <<= 1) {
    int t = (tid >= d) ? sm[tid - d] : 0;
    __syncthreads();
    if (tid >= d) sm[tid] += t;
    __syncthreads();
  }
  if (tid < nb) part[tid] = sm[tid] - v;
}

__global__ void k_scan_add(int* __restrict__ out, const int* __restrict__ part, int n) {
  int i = blockIdx.x * 256 + threadIdx.x;
  if (i < n) out[i] += part[blockIdx.x];
}

__global__ __launch_bounds__(256)
void k_bucket_scatter(const int* __restrict__ row, const int* __restrict__ col,
                      const int* __restrict__ hist, int* __restrict__ packed,
                      int E, int NB, int NBLK) {
  __shared__ int br[MAXNB], bc[MAXNB];
  for (int i = threadIdx.x; i < NB; i += 256) {
    br[i] = hist[(size_t)i * NBLK + blockIdx.x];
    bc[i] = hist[(size_t)(NB + i) * NBLK + blockIdx.x];
  }
  __syncthreads();
  int base = blockIdx.x * EBLK;
  for (int k = 0; k < KITER; k++) {
    int e = base + k * 256 + threadIdx.x;
    if (e < E) {
      int r = __builtin_nontemporal_load(&row[e]);
      int c = __builtin_nontemporal_load(&col[e]);
      int pr = atomicAdd(&br[r >> 7], 1);
      packed[pr] = (c << 7) | (r & 127);
      int pc = atomicAdd(&bc[c >> 7], 1);
      packed[pc] = (r << 7) | (c & 127);
    }
  }
}

// One block per (direction, bucket): per-node counts -> deg2 fields, offsets, sorted adj.
__global__ __launch_bounds__(256)
void k_bucket_csr(const int* __restrict__ hist, const int* __restrict__ packed,
                  int* __restrict__ adj, int2* __restrict__ deg2,
                  int* __restrict__ roff, int* __restrict__ coff,
                  int N, int NB, int NBLK, int E2) {
  __shared__ int cnt[128], scn[128], cur[128];
  int gb = blockIdx.x;            // combined bucket index in [0, 2*NB)
  int tid = threadIdx.x;
  if (tid < 128) { cnt[tid] = 0; cur[tid] = 0; }
  __syncthreads();
  int start = hist[(size_t)gb * NBLK];
  int end = (gb + 1 < gridDim.x) ? hist[(size_t)(gb + 1) * NBLK] : E2;
  for (int i = start + tid; i < end; i += 256)
    atomicAdd(&cnt[packed[i] & 127], 1);
  __syncthreads();
  if (tid == 0) {
    int a = 0;
    for (int i = 0; i < 128; i++) { scn[i] = a; a += cnt[i]; }
  }
  __syncthreads();
  if (tid < 128) {
    int b = gb < NB ? gb : gb - NB;
    int node = (b << 7) + tid;
    if (node < N) {
      if (gb < NB) { deg2[node].x = cnt[tid]; roff[node] = start + scn[tid]; }
      else         { deg2[node].y = cnt[tid]; coff[node] = start + scn[tid]; }
    }
  }
  __syncthreads();
  for (int i = start + tid; i < end; i += 256) {
    int v = packed[i];
    int l = v & 127, o = v >> 7;
    int rk = atomicAdd(&cur[l], 1);
    adj[start + scn[l] + rk] = o;
  }
}

// Second-order degree sums (CSR gathers of packed int2 degrees) + packed scale vectors.
// sclG1[n] = {isi, sAtA, sAAi, iso}; sclG2[n] = {iso, sAAt, sAAo, isi}
__global__ __launch_bounds__(256)
void k_m4scales(const int* __restrict__ roff, const int* __restrict__ coff,
                const int2* __restrict__ deg2, const int* __restrict__ adj,
                float4* __restrict__ sclG1, float4* __restrict__ sclG2, int N) {
  int n = blockIdx.x * 256 + threadIdx.x;
  if (n >= N) return;
  int2 dn = deg2[n];
  int o0 = roff[n];
  float aat = 0.f, aao = 0.f;
  for (int e = 0; e < dn.x; e++) {
    int2 dc = deg2[adj[o0 + e]];
    aat += (float)dc.y;   // Av(d_in)
    aao += (float)dc.x;   // Av(d_out)
  }
  int i0 = coff[n];
  float ata = 0.f, aai = 0.f;
  for (int e = 0; e < dn.y; e++) {
    int2 dr = deg2[adj[i0 + e]];
    ata += (float)dr.x;   // Atv(d_out)
    aai += (float)dr.y;   // Atv(d_in)
  }
  float iso = inv_sqrt_pos((float)dn.x), isi = inv_sqrt_pos((float)dn.y);
  sclG1[n] = make_float4(isi, inv_sqrt_pos(ata), inv_sqrt_pos(aai), iso);
  sclG2[n] = make_float4(iso, inv_sqrt_pos(aat), inv_sqrt_pos(aao), isi);
}

// ---------- fused first-order passes: A (out-CSR/Av) + B (in-CSR/Atv) ----------
// A: P1 -> H slot0 (*iso); Q2 -> QR2 cols0-63; R1 -> QR1 cols64-127
// B: P2 -> H slot1 (*isi); Q1 -> QR1 cols0-63; R2 -> QR2 cols64-127
// Memory discipline:
//  - adj is streamed once -> NT loads (don't evict x rows from L2)
//  - QR/H outputs written once, consumed later -> NT stores (native ext_vector
//    types: __builtin_nontemporal_store rejects HIP_vector_type structs)
//  - all gather offsets in 32-bit int arithmetic (max index 38.4M << 2^31)
// Edge loop unrolled x4 for gather MLP; launch_bounds (256,4).
#define AB_ACC(rr, ss) do { \
    float f0 = us2f((rr).x), f1 = us2f((rr).y), f2 = us2f((rr).z), f3 = us2f((rr).w); \
    a0[0] += (ss).x * f0; a0[1] += (ss).x * f1; a0[2] += (ss).x * f2; a0[3] += (ss).x * f3; \
    a1[0] += (ss).y * f0; a1[1] += (ss).y * f1; a1[2] += (ss).y * f2; a1[3] += (ss).y * f3; \
    a2[0] += (ss).z * f0; a2[1] += (ss).z * f1; a2[2] += (ss).z * f2; a2[3] += (ss).z * f3; \
  } while (0)

__global__ __launch_bounds__(256, 4)
void k_passAB(const int* __restrict__ roff, const int* __restrict__ coff,
              const int2* __restrict__ deg2, const int* __restrict__ adj,
              const bf16* __restrict__ xb,
              const float4* __restrict__ sclG1, const float4* __restrict__ sclG2,
              bf16* __restrict__ H, bf16* __restrict__ QR1, bf16* __restrict__ QR2,
              int N, int gW) {
  int side = (int)(blockIdx.x & 1);       // interleave A/B in dispatch order
  int lb = (int)(blockIdx.x >> 1);
  int wid = (lb * 256 + (int)threadIdx.x) >> 6;
  if (wid >= N) return;
  int lane = threadIdx.x & 63;
  int q = lane >> 4, t4 = (lane & 15) << 2;
  int o, d; const float4* sclG; bf16 *outP, *outOwn, *outOth;
  if (!side) { o = roff[wid]; d = deg2[wid].x; sclG = sclG1;
               outP = H + 0 * 64; outOwn = QR2; outOth = QR1; }
  else       { o = coff[wid]; d = deg2[wid].y; sclG = sclG2;
               outP = H + 1 * 64; outOwn = QR1; outOth = QR2; }
  float a0[4] = {0,0,0,0}, a1[4] = {0,0,0,0}, a2[4] = {0,0,0,0};
  int e = q;
  // main loop: 4 edges per quarter-wave in flight (16 per wave)
  for (; e + 12 < d; e += 16) {
    int nb0 = __builtin_nontemporal_load(&adj[o + e]);
    int nb1 = __builtin_nontemporal_load(&adj[o + e + 4]);
    int nb2 = __builtin_nontemporal_load(&adj[o + e + 8]);
    int nb3 = __builtin_nontemporal_load(&adj[o + e + 12]);
    ushort4 r0 = *(const ushort4*)(xb + ((nb0 << 6) | t4));
    ushort4 r1 = *(const ushort4*)(xb + ((nb1 << 6) | t4));
    ushort4 r2 = *(const ushort4*)(xb + ((nb2 << 6) | t4));
    ushort4 r3 = *(const ushort4*)(xb + ((nb3 << 6) | t4));
    float4 s0 = sclG[nb0];
    float4 s1 = sclG[nb1];
    float4 s2 = sclG[nb2];
    float4 s3 = sclG[nb3];
    AB_ACC(r0, s0); AB_ACC(r1, s1); AB_ACC(r2, s2); AB_ACC(r3, s3);
  }
  for (; e < d; e += 4) {
    int nb = __builtin_nontemporal_load(&adj[o + e]);
    ushort4 r = *(const ushort4*)(xb + ((nb << 6) | t4));
    float4 s = sclG[nb];
    AB_ACC(r, s);
  }
  #pragma unroll
  for (int i = 0; i < 4; i++) {
    a0[i] += __shfl_xor(a0[i], 16); a0[i] += __shfl_xor(a0[i], 32);
    a1[i] += __shfl_xor(a1[i], 16); a1[i] += __shfl_xor(a1[i], 32);
    a2[i] += __shfl_xor(a2[i], 16); a2[i] += __shfl_xor(a2[i], 32);
  }
  if (q == 0) {
    float w = sclG[wid].w;
    u16x4 uP, uQ, uR;
    uP[0] = f2bu(a0[0]*w); uP[1] = f2bu(a0[1]*w); uP[2] = f2bu(a0[2]*w); uP[3] = f2bu(a0[3]*w);
    uQ[0] = f2bu(a1[0]);   uQ[1] = f2bu(a1[1]);   uQ[2] = f2bu(a1[2]);   uQ[3] = f2bu(a1[3]);
    uR[0] = f2bu(a2[0]);   uR[1] = f2bu(a2[1]);   uR[2] = f2bu(a2[2]);   uR[3] = f2bu(a2[3]);
    __builtin_nontemporal_store(uP, (u16x4*)(outP + wid * KTOT + t4));
    __builtin_nontemporal_store(uQ, (u16x4*)(outOwn + (wid << 7) + t4));
    __builtin_nontemporal_store(uR, (u16x4*)(outOth + (wid << 7) + 64 + t4));
  }
}

// ---------- fused second-order passes: C (out-CSR, QR1) + D (in-CSR, QR2) ----------
// One contiguous 256B gather per edge (16 lanes x uint4).
// C: S0=sAAt*Av(Q1)->slot2, S2=sAAo*Av(R1)->slot4;  D: S1=sAtA*Atv(Q2)->slot3, S3=sAAi*Atv(R2)->slot5
// Sides kept SEQUENTIAL (C then D): they gather different arrays. NT adj loads,
// NT H stores, 32-bit gather offsets (same rationale as k_passAB).
#define CD_ACC(vv) do { \
    acc[0] += us2f((vv).x & 0xffff); acc[1] += us2f((vv).x >> 16); \
    acc[2] += us2f((vv).y & 0xffff); acc[3] += us2f((vv).y >> 16); \
    acc[4] += us2f((vv).z & 0xffff); acc[5] += us2f((vv).z >> 16); \
    acc[6] += us2f((vv).w & 0xffff); acc[7] += us2f((vv).w >> 16); \
  } while (0)

__global__ __launch_bounds__(256, 4)
void k_passCD(const int* __restrict__ roff, const int* __restrict__ coff,
              const int2* __restrict__ deg2, const int* __restrict__ adj,
              const bf16* __restrict__ QR1, const bf16* __restrict__ QR2,
              const float4* __restrict__ sclG1, const float4* __restrict__ sclG2,
              bf16* __restrict__ H, int N, int gW) {
  int side = (blockIdx.x >= gW);   // 0 = C, 1 = D
  int lb = side ? blockIdx.x - gW : blockIdx.x;
  int wid = (lb * 256 + (int)threadIdx.x) >> 6;
  if (wid >= N) return;
  int lane = threadIdx.x & 63;
  int q = lane >> 4, t = lane & 15;
  int o, d; const bf16* QR;
  if (!side) { o = roff[wid]; d = deg2[wid].x; QR = QR1; }
  else       { o = coff[wid]; d = deg2[wid].y; QR = QR2; }
  int t8 = t << 3;
  float acc[8] = {0,0,0,0,0,0,0,0};
  int e = q;
  for (; e + 12 < d; e += 16) {
    int nb0 = __builtin_nontemporal_load(&adj[o + e]);
    int nb1 = __builtin_nontemporal_load(&adj[o + e + 4]);
    int nb2 = __builtin_nontemporal_load(&adj[o + e + 8]);
    int nb3 = __builtin_nontemporal_load(&adj[o + e + 12]);
    uint4 v0 = *(const uint4*)(QR + ((nb0 << 7) | t8));
    uint4 v1 = *(const uint4*)(QR + ((nb1 << 7) | t8));
    uint4 v2 = *(const uint4*)(QR + ((nb2 << 7) | t8));
    uint4 v3 = *(const uint4*)(QR + ((nb3 << 7) | t8));
    CD_ACC(v0); CD_ACC(v1); CD_ACC(v2); CD_ACC(v3);
  }
  for (; e < d; e += 4) {
    int nb = __builtin_nontemporal_load(&adj[o + e]);
    uint4 v = *(const uint4*)(QR + ((nb << 7) | t8));
    CD_ACC(v);
  }
  #pragma unroll
  for (int i = 0; i < 8; i++) {
    acc[i] += __shfl_xor(acc[i], 16);
    acc[i] += __shfl_xor(acc[i], 32);
  }
  if (q == 0) {
    float4 s = side ? sclG1[wid] : sclG2[wid];
    float ws = (t < 8) ? s.y : s.z;
    int slot = side ? (t < 8 ? 3 : 5) : (t < 8 ? 2 : 4);
    int col = slot * 64 + (t & 7) * 8;
    u32x4 ov;
    ov[0] = pack2(acc[0]*ws, acc[1]*ws);
    ov[1] = pack2(acc[2]*ws, acc[3]*ws);
    ov[2] = pack2(acc[4]*ws, acc[5]*ws);
    ov[3] = pack2(acc[6]*ws, acc[7]*ws);
    __builtin_nontemporal_store(ov, (u32x4*)(H + wid * KTOT + col));
  }
}

// ---------- final MFMA GEMM: out[N,64] = 0.75*(H[N,384] @ Wcat[384,64] + bsum) ----------
__global__ __launch_bounds__(256)
void k_final(const bf16* __restrict__ H, const bf16* __restrict__ wt,
             const float* __restrict__ bsum, void* __restrict__ outv,
             const int* __restrict__ cnt, int N) {
  __shared__ bf16 Wl[64 * LDSK];
  {
    const unsigned int* wtu = (const unsigned int*)wt;
    unsigned int* wlu = (unsigned int*)Wl;
    for (int i = threadIdx.x; i < 64 * (KTOT / 2); i += 256) {
      int n = i / (KTOT / 2), k2 = i % (KTOT / 2);
      wlu[n * (LDSK / 2) + k2] = wtu[i];
    }
  }
  __syncthreads();

  int wave = threadIdx.x >> 6, lane = threadIdx.x & 63;
  int m0 = blockIdx.x * 64 + wave * 16;
  int ml = lane & 15, kq = lane >> 4;
  const bf16* Hrow = H + (m0 + ml) * KTOT + kq * 8;

  f32x4 acc[4] = {{0,0,0,0},{0,0,0,0},{0,0,0,0},{0,0,0,0}};
  #pragma unroll
  for (int kb = 0; kb < KTOT / 32; kb++) {
    bf16x8 a = __builtin_nontemporal_load((const bf16x8*)(Hrow + kb * 32));
    #pragma unroll
    for (int ct = 0; ct < 4; ct++) {
      bf16x8 b = *(const bf16x8*)(Wl + (ct * 16 + ml) * LDSK + kb * 32 + kq * 8);
      acc[ct] = __builtin_amdgcn_mfma_f32_16x16x32_bf16(a, b, acc[ct], 0, 0, 0);
    }
  }

  bool fp = (*cnt > SNIFF_THRESH);
  #pragma unroll
  for (int ct = 0; ct < 4; ct++) {
    int col = ct * 16 + ml;
    float bias = bsum[col];
    #pragma unroll
    for (int r = 0; r < 4; r++) {
      int m = m0 + kq * 4 + r;
      if (m < N) {
        float val = 0.75f * (acc[ct][r] + bias);
        if (fp) ((float*)outv)[m * FDIM + col] = val;
        else    ((bf16*)outv)[m * FDIM + col] = __float2bfloat16(val);
      }
    }
  }
}

// ---------- host ----------
extern "C" void kernel_launch(void* const* d_in, const int* in_sizes, int n_in,
                              void* d_out, int out_size, void* d_ws, size_t ws_size,
                              hipStream_t stream) {
  const void* x = d_in[0];
  const int* ei = (const int*)d_in[1];
  int NX = in_sizes[0];
  int N = NX / FDIM;
  int E = in_sizes[1] / 2;
  const int* row = ei;
  const int* col = ei + E;

  char* p = (char*)d_ws;
  auto alloc = [&](size_t bytes) {
    bytes = (bytes + 255) & ~(size_t)255;
    char* r = p; p += bytes; return r;
  };

  int*   cnt  = (int*)alloc(4);            // zero-init region start
  int2*  deg2 = (int2*)alloc((size_t)N * 8);
  int* roff   = (int*)alloc((size_t)N * 4);
  int* coff   = (int*)alloc((size_t)N * 4);
  int* p1     = (int*)alloc(8192 * 4);
  int* p2     = (int*)alloc(1024 * 4);
  float4* sclG1 = (float4*)alloc((size_t)N * 16);
  float4* sclG2 = (float4*)alloc((size_t)N * 16);
  int* adj    = (int*)alloc((size_t)2 * E * 4);  // [0,E)=out-CSR, [E,2E)=in-CSR
  bf16* xb    = (bf16*)alloc((size_t)NX * 2);
  bf16* wt    = (bf16*)alloc((size_t)6 * 4096 * 2);
  float* bsum = (float*)alloc(64 * 4);
  bf16* H   = (bf16*)alloc((size_t)N * KTOT * 2); // 6 concatenated 64-col slots
  bf16* QR1 = (bf16*)alloc((size_t)N * 128 * 2);  // [Q1 | R1]
  bf16* QR2 = (bf16*)alloc((size_t)N * 128 * 2);  // [Q2 | R2]

  // dead-before-use aliases (consumed in CSR build, before QR1/H are written)
  int* hist   = (int*)QR1;  // 2*NB*NBLK ints (~2.4 MB <= 25.6 MB)
  int* packed = (int*)H;    // 2*E ints (12.8 MB <= 76.8 MB)

  hipMemsetAsync(d_ws, 0, 256, stream);

  int gN = (N + 255) / 256;
  int gW = (N + 3) / 4;      // wave-per-node kernels: 4 waves/block
  int gF = (N + 63) / 64;

  int NB   = (N + 127) >> 7;
  int NBLK = (E + EBLK - 1) / EBLK;
  int lenH = 2 * NB * NBLK;
  int g0 = (lenH + 255) / 256;
  int g1 = (g0 + 255) / 256;

  // dtype canonicalization (sampled sniff: 1M elements, 1 atomic/block)
  int nSniff = NX < (1 << 20) ? NX : (1 << 20);
  k_sniff<<<256, 256, 0, stream>>>((const unsigned short*)x, nSniff, cnt);
  int n4 = NX / 4;
  k_convert_x<<<(n4 + 255) / 256, 256, 0, stream>>>(x, xb, cnt, n4);
  k_convert_w<<<98, 256, 0, stream>>>(d_in[2], d_in[4], d_in[6], d_in[8], d_in[10], d_in[12],
                                      d_in[3], d_in[5], d_in[7], d_in[9], d_in[11], d_in[13],
                                      wt, bsum, cnt);

  // CSR build: histogram -> scan -> bucket scatter -> per-bucket sort (no global atomics)
  k_hist<<<NBLK, 256, 0, stream>>>(row, col, hist, E, NB, NBLK);
  k_scan_block<<<g0, 256, 0, stream>>>(hist, hist, p1, lenH);
  k_scan_block<<<g1, 256, 0, stream>>>(p1, p1, p2, g0);
  k_scan_part<<<1, 1024, 0, stream>>>(p2, g1);
  k_scan_add<<<g1, 256, 0, stream>>>(p1, p2, g0);
  k_scan_add<<<g0, 256, 0, stream>>>(hist, p1, lenH);
  k_bucket_scatter<<<NBLK, 256, 0, stream>>>(row, col, hist, packed, E, NB, NBLK);
  k_bucket_csr<<<2 * NB, 256, 0, stream>>>(hist, packed, adj, deg2, roff, coff,
                                           N, NB, NBLK, 2 * E);
  k_m4scales<<<gN, 256, 0, stream>>>(roff, coff, deg2, adj, sclG1, sclG2, N);

  // fused first-order (A+B, side-interleaved) and second-order (C+D) passes
  k_passAB<<<2 * gW, 256, 0, stream>>>(roff, coff, deg2, adj, xb, sclG1, sclG2,
                                       H, QR1, QR2, N, gW);
  k_passCD<<<2 * gW, 256, 0, stream>>>(roff, coff, deg2, adj, QR1, QR2, sclG1, sclG2,
                                       H, N, gW);

  // out = 0.75 * (H @ Wcat + bsum)
  k_final<<<gF, 256, 0, stream>>>(H, wt, bsum, d_out, cnt, N);
}

// Round 6
// 500.617 us; speedup vs baseline: 1.1153x; 1.1153x over previous
//
#include <hip/hip_runtime.h>
#include <hip/hip_bf16.h>

typedef __hip_bfloat16 bf16;
typedef __bf16 bf16x8 __attribute__((ext_vector_type(8)));
typedef float f32x4 __attribute__((ext_vector_type(4)));
typedef unsigned short u16x4 __attribute__((ext_vector_type(4)));
typedef unsigned int u32x4 __attribute__((ext_vector_type(4)));
#define FDIM 64
#define KTOT 384
#define LDSK 392   // padded K-stride for W^T in LDS
#define SNIFF_THRESH 100
#define MAXNB 1024 // max node buckets (supports N <= 131072; here N=100K -> 782)
#define EBLK 8192  // edges per CSR-build block
#define KITER (EBLK / 256)

__device__ __forceinline__ float us2f(unsigned short u) {
  union { unsigned int i; float f; } v; v.i = ((unsigned int)u) << 16; return v.f;
}
__device__ __forceinline__ unsigned short f2bu(float v) {
  bf16 h = __float2bfloat16(v);
  return *(unsigned short*)&h;
}
__device__ __forceinline__ unsigned int pack2(float a, float b) {
  return (unsigned int)f2bu(a) | ((unsigned int)f2bu(b) << 16);
}
__device__ __forceinline__ float inv_sqrt_pos(float d) { return d > 0.f ? rsqrtf(d) : 0.f; }

// ---------- dtype sniffing & canonicalization ----------
__global__ __launch_bounds__(256)
void k_sniff(const unsigned short* __restrict__ xs, int n, int* __restrict__ cnt) {
  int local = 0;
  for (int i = blockIdx.x * 256 + threadIdx.x; i < n; i += 256 * 256)
    local += ((xs[i] & 0x7F80) == 0x7F80) ? 1 : 0;
  #pragma unroll
  for (int d = 32; d >= 1; d >>= 1) local += __shfl_down(local, d);
  __shared__ int sm[4];
  if ((threadIdx.x & 63) == 0) sm[threadIdx.x >> 6] = local;
  __syncthreads();
  if (threadIdx.x == 0) {
    int t = sm[0] + sm[1] + sm[2] + sm[3];
    if (t) atomicAdd(cnt, t);
  }
}

// Vectorized: 4 elements per thread. n4 = n/4.
__global__ __launch_bounds__(256)
void k_convert_x(const void* __restrict__ xin, bf16* __restrict__ xb,
                 const int* __restrict__ cnt, int n4) {
  int i = blockIdx.x * 256 + threadIdx.x;
  if (i >= n4) return;
  ushort4 o;
  if (*cnt > SNIFF_THRESH) {
    float4 v = ((const float4*)xin)[i];
    o.x = f2bu(v.x); o.y = f2bu(v.y); o.z = f2bu(v.z); o.w = f2bu(v.w);
  } else {
    o = ((const ushort4*)xin)[i];
  }
  ((ushort4*)xb)[i] = o;
}

// W^T-concat: wt[n*384 + si*64 + kk] = W_si[kk][n]; bsum[n] = sum_si b_si[n] (fp32)
__global__ void k_convert_w(const void* W0, const void* W1, const void* W2,
                            const void* W3, const void* W4, const void* W5,
                            const void* c0, const void* c1, const void* c2,
                            const void* c3, const void* c4, const void* c5,
                            bf16* __restrict__ wt, float* __restrict__ bsum,
                            const int* __restrict__ cnt) {
  int t = blockIdx.x * 256 + threadIdx.x;
  const void* Ws[6] = {W0, W1, W2, W3, W4, W5};
  const void* Bs[6] = {c0, c1, c2, c3, c4, c5};
  bool fp = (*cnt > SNIFF_THRESH);
  if (t < 6 * 4096) {
    int si = t >> 12, o = t & 4095;
    int kk = o >> 6, n = o & 63;
    float v = fp ? ((const float*)Ws[si])[o] : __bfloat162float(((const bf16*)Ws[si])[o]);
    wt[n * KTOT + si * 64 + kk] = __float2bfloat16(v);
  } else if (t < 6 * 4096 + 64) {
    int n = t - 6 * 4096;
    float s = 0.f;
    for (int si = 0; si < 6; si++)
      s += fp ? ((const float*)Bs[si])[n] : __bfloat162float(((const bf16*)Bs[si])[n]);
    bsum[n] = s;
  }
}

// ---------- CSR build via LDS counting sort (no global atomics) ----------
__global__ __launch_bounds__(256)
void k_hist(const int* __restrict__ row, const int* __restrict__ col,
            int* __restrict__ hist, int E, int NB, int NBLK) {
  __shared__ int hr[MAXNB], hc[MAXNB];
  for (int i = threadIdx.x; i < NB; i += 256) { hr[i] = 0; hc[i] = 0; }
  __syncthreads();
  int base = blockIdx.x * EBLK;
  for (int k = 0; k < KITER; k++) {
    int e = base + k * 256 + threadIdx.x;
    if (e < E) {
      atomicAdd(&hr[row[e] >> 7], 1);
      atomicAdd(&hc[col[e] >> 7], 1);
    }
  }
  __syncthreads();
  for (int i = threadIdx.x; i < NB; i += 256) {
    hist[(size_t)i * NBLK + blockIdx.x] = hr[i];
    hist[(size_t)(NB + i) * NBLK + blockIdx.x] = hc[i];
  }
}

__global__ void k_scan_block(const int* __restrict__ in, int* __restrict__ out,
                             int* __restrict__ part, int n) {
  __shared__ int sm[256];
  int tid = threadIdx.x;
  int i = blockIdx.x * 256 + tid;
  int v = (i < n) ? in[i] : 0;
  sm[tid] = v;
  __syncthreads();
  for (int d = 1; d < 256; d <<= 1) {
    int t = (tid >= d) ? sm[tid - d] : 0;
    __syncthreads();
    if (tid >= d) sm[tid] += t;
    __syncthreads();
  }
  if (i < n) out[i] = sm[tid] - v;
  if (tid == 255) part[blockIdx.x] = sm[255];
}

__global__ void k_scan_part(int* part, int nb) {
  __shared__ int sm[1024];
  int tid = threadIdx.x;
  int v = (tid < nb) ? part[tid] : 0;
  sm[tid] = v;
  __syncthreads();
  for (int d = 1; d < 1024; d <<= 1) {
    int t = (tid >= d) ? sm[tid - d] : 0;
    __syncthreads();
    if (tid >= d) sm[tid] += t;
    __syncthreads();
  }
  if (tid < nb) part[tid] = sm[tid] - v;
}

__global__ void k_scan_add(int* __restrict__ out, const int* __restrict__ part, int n) {
  int i = blockIdx.x * 256 + threadIdx.x;
  if (i < n) out[i] += part[blockIdx.x];
}

__global__ __launch_bounds__(256)
void k_bucket_scatter(const int* __restrict__ row, const int* __restrict__ col,
                      const int* __restrict__ hist, int* __restrict__ packed,
                      int E, int NB, int NBLK) {
  __shared__ int br[MAXNB], bc[MAXNB];
  for (int i = threadIdx.x; i < NB; i += 256) {
    br[i] = hist[(size_t)i * NBLK + blockIdx.x];
    bc[i] = hist[(size_t)(NB + i) * NBLK + blockIdx.x];
  }
  __syncthreads();
  int base = blockIdx.x * EBLK;
  for (int k = 0; k < KITER; k++) {
    int e = base + k * 256 + threadIdx.x;
    if (e < E) {
      int r = row[e], c = col[e];
      int pr = atomicAdd(&br[r >> 7], 1);
      packed[pr] = (c << 7) | (r & 127);
      int pc = atomicAdd(&bc[c >> 7], 1);
      packed[pc] = (r << 7) | (c & 127);
    }
  }
}

// One block per (direction, bucket): per-node counts -> deg2 fields, offsets, sorted adj.
__global__ __launch_bounds__(256)
void k_bucket_csr(const int* __restrict__ hist, const int* __restrict__ packed,
                  int* __restrict__ adj, int2* __restrict__ deg2,
                  int* __restrict__ roff, int* __restrict__ coff,
                  int N, int NB, int NBLK, int E2) {
  __shared__ int cnt[128], scn[128], cur[128];
  int gb = blockIdx.x;            // combined bucket index in [0, 2*NB)
  int tid = threadIdx.x;
  if (tid < 128) { cnt[tid] = 0; cur[tid] = 0; }
  __syncthreads();
  int start = hist[(size_t)gb * NBLK];
  int end = (gb + 1 < gridDim.x) ? hist[(size_t)(gb + 1) * NBLK] : E2;
  for (int i = start + tid; i < end; i += 256)
    atomicAdd(&cnt[packed[i] & 127], 1);
  __syncthreads();
  if (tid == 0) {
    int a = 0;
    for (int i = 0; i < 128; i++) { scn[i] = a; a += cnt[i]; }
  }
  __syncthreads();
  if (tid < 128) {
    int b = gb < NB ? gb : gb - NB;
    int node = (b << 7) + tid;
    if (node < N) {
      if (gb < NB) { deg2[node].x = cnt[tid]; roff[node] = start + scn[tid]; }
      else         { deg2[node].y = cnt[tid]; coff[node] = start + scn[tid]; }
    }
  }
  __syncthreads();
  for (int i = start + tid; i < end; i += 256) {
    int v = packed[i];
    int l = v & 127, o = v >> 7;
    int rk = atomicAdd(&cur[l], 1);
    adj[start + scn[l] + rk] = o;
  }
}

// Second-order degree sums (CSR gathers of packed int2 degrees) + packed scale vectors.
// sclG1[n] = {isi, sAtA, sAAi, iso}; sclG2[n] = {iso, sAAt, sAAo, isi}
__global__ __launch_bounds__(256)
void k_m4scales(const int* __restrict__ roff, const int* __restrict__ coff,
                const int2* __restrict__ deg2, const int* __restrict__ adj,
                float4* __restrict__ sclG1, float4* __restrict__ sclG2, int N) {
  int n = blockIdx.x * 256 + threadIdx.x;
  if (n >= N) return;
  int2 dn = deg2[n];
  int o0 = roff[n];
  float aat = 0.f, aao = 0.f;
  for (int e = 0; e < dn.x; e++) {
    int2 dc = deg2[adj[o0 + e]];
    aat += (float)dc.y;   // Av(d_in)
    aao += (float)dc.x;   // Av(d_out)
  }
  int i0 = coff[n];
  float ata = 0.f, aai = 0.f;
  for (int e = 0; e < dn.y; e++) {
    int2 dr = deg2[adj[i0 + e]];
    ata += (float)dr.x;   // Atv(d_out)
    aai += (float)dr.y;   // Atv(d_in)
  }
  float iso = inv_sqrt_pos((float)dn.x), isi = inv_sqrt_pos((float)dn.y);
  sclG1[n] = make_float4(isi, inv_sqrt_pos(ata), inv_sqrt_pos(aai), iso);
  sclG2[n] = make_float4(iso, inv_sqrt_pos(aat), inv_sqrt_pos(aao), isi);
}

// ---------- fused first-order passes: A (out-CSR/Av) + B (in-CSR/Atv) ----------
// A: P1 -> H slot0 (*iso); Q2 -> QR2 cols0-63; R1 -> QR1 cols64-127
// B: P2 -> H slot1 (*isi); Q1 -> QR1 cols0-63; R2 -> QR2 cols64-127
// Sides interleaved at block granularity (side = blockIdx&1).
// All gather offsets in 32-bit int arithmetic (max index 38.4M << 2^31) --
// avoids 64-bit VGPR-pair address math per gather (R5: VALUBusy 51->46.6%).
// NT hints removed (R5: NT load/store regressed passAB 133->149 us -- adj has
// short-term L2 reuse; NT stores serialize to HBM and starve later readers).
// Edge loop unrolled x4 for gather MLP; launch_bounds (256,4).
#define AB_ACC(rr, ss) do { \
    float f0 = us2f((rr).x), f1 = us2f((rr).y), f2 = us2f((rr).z), f3 = us2f((rr).w); \
    a0[0] += (ss).x * f0; a0[1] += (ss).x * f1; a0[2] += (ss).x * f2; a0[3] += (ss).x * f3; \
    a1[0] += (ss).y * f0; a1[1] += (ss).y * f1; a1[2] += (ss).y * f2; a1[3] += (ss).y * f3; \
    a2[0] += (ss).z * f0; a2[1] += (ss).z * f1; a2[2] += (ss).z * f2; a2[3] += (ss).z * f3; \
  } while (0)

__global__ __launch_bounds__(256, 4)
void k_passAB(const int* __restrict__ roff, const int* __restrict__ coff,
              const int2* __restrict__ deg2, const int* __restrict__ adj,
              const bf16* __restrict__ xb,
              const float4* __restrict__ sclG1, const float4* __restrict__ sclG2,
              bf16* __restrict__ H, bf16* __restrict__ QR1, bf16* __restrict__ QR2,
              int N, int gW) {
  int side = (int)(blockIdx.x & 1);       // interleave A/B in dispatch order
  int lb = (int)(blockIdx.x >> 1);
  int wid = (lb * 256 + (int)threadIdx.x) >> 6;
  if (wid >= N) return;
  int lane = threadIdx.x & 63;
  int q = lane >> 4, t4 = (lane & 15) << 2;
  int o, d; const float4* sclG; bf16 *outP, *outOwn, *outOth;
  if (!side) { o = roff[wid]; d = deg2[wid].x; sclG = sclG1;
               outP = H + 0 * 64; outOwn = QR2; outOth = QR1; }
  else       { o = coff[wid]; d = deg2[wid].y; sclG = sclG2;
               outP = H + 1 * 64; outOwn = QR1; outOth = QR2; }
  float a0[4] = {0,0,0,0}, a1[4] = {0,0,0,0}, a2[4] = {0,0,0,0};
  int e = q;
  // main loop: 4 edges per quarter-wave in flight (16 per wave)
  for (; e + 12 < d; e += 16) {
    int nb0 = adj[o + e];
    int nb1 = adj[o + e + 4];
    int nb2 = adj[o + e + 8];
    int nb3 = adj[o + e + 12];
    ushort4 r0 = *(const ushort4*)(xb + ((nb0 << 6) | t4));
    ushort4 r1 = *(const ushort4*)(xb + ((nb1 << 6) | t4));
    ushort4 r2 = *(const ushort4*)(xb + ((nb2 << 6) | t4));
    ushort4 r3 = *(const ushort4*)(xb + ((nb3 << 6) | t4));
    float4 s0 = sclG[nb0];
    float4 s1 = sclG[nb1];
    float4 s2 = sclG[nb2];
    float4 s3 = sclG[nb3];
    AB_ACC(r0, s0); AB_ACC(r1, s1); AB_ACC(r2, s2); AB_ACC(r3, s3);
  }
  for (; e < d; e += 4) {
    int nb = adj[o + e];
    ushort4 r = *(const ushort4*)(xb + ((nb << 6) | t4));
    float4 s = sclG[nb];
    AB_ACC(r, s);
  }
  #pragma unroll
  for (int i = 0; i < 4; i++) {
    a0[i] += __shfl_xor(a0[i], 16); a0[i] += __shfl_xor(a0[i], 32);
    a1[i] += __shfl_xor(a1[i], 16); a1[i] += __shfl_xor(a1[i], 32);
    a2[i] += __shfl_xor(a2[i], 16); a2[i] += __shfl_xor(a2[i], 32);
  }
  if (q == 0) {
    float w = sclG[wid].w;
    ushort4 uP, uQ, uR;
    uP.x = f2bu(a0[0]*w); uP.y = f2bu(a0[1]*w); uP.z = f2bu(a0[2]*w); uP.w = f2bu(a0[3]*w);
    uQ.x = f2bu(a1[0]);   uQ.y = f2bu(a1[1]);   uQ.z = f2bu(a1[2]);   uQ.w = f2bu(a1[3]);
    uR.x = f2bu(a2[0]);   uR.y = f2bu(a2[1]);   uR.z = f2bu(a2[2]);   uR.w = f2bu(a2[3]);
    *(ushort4*)(outP + wid * KTOT + t4) = uP;
    *(ushort4*)(outOwn + (wid << 7) + t4) = uQ;
    *(ushort4*)(outOth + (wid << 7) + 64 + t4) = uR;
  }
}

// ---------- fused second-order passes: C (out-CSR, QR1) + D (in-CSR, QR2) ----------
// One contiguous 256B gather per edge (16 lanes x uint4).
// C: S0=sAAt*Av(Q1)->slot2, S2=sAAo*Av(R1)->slot4;  D: S1=sAtA*Atv(Q2)->slot3, S3=sAAi*Atv(R2)->slot5
// Sides kept SEQUENTIAL (C then D): they gather different arrays.
// 32-bit gather offsets (same rationale as k_passAB). No NT hints (R5 lesson).
#define CD_ACC(vv) do { \
    acc[0] += us2f((vv).x & 0xffff); acc[1] += us2f((vv).x >> 16); \
    acc[2] += us2f((vv).y & 0xffff); acc[3] += us2f((vv).y >> 16); \
    acc[4] += us2f((vv).z & 0xffff); acc[5] += us2f((vv).z >> 16); \
    acc[6] += us2f((vv).w & 0xffff); acc[7] += us2f((vv).w >> 16); \
  } while (0)

__global__ __launch_bounds__(256, 4)
void k_passCD(const int* __restrict__ roff, const int* __restrict__ coff,
              const int2* __restrict__ deg2, const int* __restrict__ adj,
              const bf16* __restrict__ QR1, const bf16* __restrict__ QR2,
              const float4* __restrict__ sclG1, const float4* __restrict__ sclG2,
              bf16* __restrict__ H, int N, int gW) {
  int side = (blockIdx.x >= gW);   // 0 = C, 1 = D
  int lb = side ? blockIdx.x - gW : blockIdx.x;
  int wid = (lb * 256 + (int)threadIdx.x) >> 6;
  if (wid >= N) return;
  int lane = threadIdx.x & 63;
  int q = lane >> 4, t = lane & 15;
  int o, d; const bf16* QR;
  if (!side) { o = roff[wid]; d = deg2[wid].x; QR = QR1; }
  else       { o = coff[wid]; d = deg2[wid].y; QR = QR2; }
  int t8 = t << 3;
  float acc[8] = {0,0,0,0,0,0,0,0};
  int e = q;
  for (; e + 12 < d; e += 16) {
    int nb0 = adj[o + e];
    int nb1 = adj[o + e + 4];
    int nb2 = adj[o + e + 8];
    int nb3 = adj[o + e + 12];
    uint4 v0 = *(const uint4*)(QR + ((nb0 << 7) | t8));
    uint4 v1 = *(const uint4*)(QR + ((nb1 << 7) | t8));
    uint4 v2 = *(const uint4*)(QR + ((nb2 << 7) | t8));
    uint4 v3 = *(const uint4*)(QR + ((nb3 << 7) | t8));
    CD_ACC(v0); CD_ACC(v1); CD_ACC(v2); CD_ACC(v3);
  }
  for (; e < d; e += 4) {
    int nb = adj[o + e];
    uint4 v = *(const uint4*)(QR + ((nb << 7) | t8));
    CD_ACC(v);
  }
  #pragma unroll
  for (int i = 0; i < 8; i++) {
    acc[i] += __shfl_xor(acc[i], 16);
    acc[i] += __shfl_xor(acc[i], 32);
  }
  if (q == 0) {
    float4 s = side ? sclG1[wid] : sclG2[wid];
    float ws = (t < 8) ? s.y : s.z;
    int slot = side ? (t < 8 ? 3 : 5) : (t < 8 ? 2 : 4);
    int col = slot * 64 + (t & 7) * 8;
    uint4 ov;
    ov.x = pack2(acc[0]*ws, acc[1]*ws);
    ov.y = pack2(acc[2]*ws, acc[3]*ws);
    ov.z = pack2(acc[4]*ws, acc[5]*ws);
    ov.w = pack2(acc[6]*ws, acc[7]*ws);
    *(uint4*)(H + wid * KTOT + col) = ov;
  }
}

// ---------- final MFMA GEMM: out[N,64] = 0.75*(H[N,384] @ Wcat[384,64] + bsum) ----------
__global__ __launch_bounds__(256)
void k_final(const bf16* __restrict__ H, const bf16* __restrict__ wt,
             const float* __restrict__ bsum, void* __restrict__ outv,
             const int* __restrict__ cnt, int N) {
  __shared__ bf16 Wl[64 * LDSK];
  {
    const unsigned int* wtu = (const unsigned int*)wt;
    unsigned int* wlu = (unsigned int*)Wl;
    for (int i = threadIdx.x; i < 64 * (KTOT / 2); i += 256) {
      int n = i / (KTOT / 2), k2 = i % (KTOT / 2);
      wlu[n * (LDSK / 2) + k2] = wtu[i];
    }
  }
  __syncthreads();

  int wave = threadIdx.x >> 6, lane = threadIdx.x & 63;
  int m0 = blockIdx.x * 64 + wave * 16;
  int ml = lane & 15, kq = lane >> 4;
  const bf16* Hrow = H + (m0 + ml) * KTOT + kq * 8;

  f32x4 acc[4] = {{0,0,0,0},{0,0,0,0},{0,0,0,0},{0,0,0,0}};
  #pragma unroll
  for (int kb = 0; kb < KTOT / 32; kb++) {
    bf16x8 a = *(const bf16x8*)(Hrow + kb * 32);
    #pragma unroll
    for (int ct = 0; ct < 4; ct++) {
      bf16x8 b = *(const bf16x8*)(Wl + (ct * 16 + ml) * LDSK + kb * 32 + kq * 8);
      acc[ct] = __builtin_amdgcn_mfma_f32_16x16x32_bf16(a, b, acc[ct], 0, 0, 0);
    }
  }

  bool fp = (*cnt > SNIFF_THRESH);
  #pragma unroll
  for (int ct = 0; ct < 4; ct++) {
    int col = ct * 16 + ml;
    float bias = bsum[col];
    #pragma unroll
    for (int r = 0; r < 4; r++) {
      int m = m0 + kq * 4 + r;
      if (m < N) {
        float val = 0.75f * (acc[ct][r] + bias);
        if (fp) ((float*)outv)[m * FDIM + col] = val;
        else    ((bf16*)outv)[m * FDIM + col] = __float2bfloat16(val);
      }
    }
  }
}

// ---------- host ----------
extern "C" void kernel_launch(void* const* d_in, const int* in_sizes, int n_in,
                              void* d_out, int out_size, void* d_ws, size_t ws_size,
                              hipStream_t stream) {
  const void* x = d_in[0];
  const int* ei = (const int*)d_in[1];
  int NX = in_sizes[0];
  int N = NX / FDIM;
  int E = in_sizes[1] / 2;
  const int* row = ei;
  const int* col = ei + E;

  char* p = (char*)d_ws;
  auto alloc = [&](size_t bytes) {
    bytes = (bytes + 255) & ~(size_t)255;
    char* r = p; p += bytes; return r;
  };

  int*   cnt  = (int*)alloc(4);            // zero-init region start
  int2*  deg2 = (int2*)alloc((size_t)N * 8);
  int* roff   = (int*)alloc((size_t)N * 4);
  int* coff   = (int*)alloc((size_t)N * 4);
  int* p1     = (int*)alloc(8192 * 4);
  int* p2     = (int*)alloc(1024 * 4);
  float4* sclG1 = (float4*)alloc((size_t)N * 16);
  float4* sclG2 = (float4*)alloc((size_t)N * 16);
  int* adj    = (int*)alloc((size_t)2 * E * 4);  // [0,E)=out-CSR, [E,2E)=in-CSR
  bf16* xb    = (bf16*)alloc((size_t)NX * 2);
  bf16* wt    = (bf16*)alloc((size_t)6 * 4096 * 2);
  float* bsum = (float*)alloc(64 * 4);
  bf16* H   = (bf16*)alloc((size_t)N * KTOT * 2); // 6 concatenated 64-col slots
  bf16* QR1 = (bf16*)alloc((size_t)N * 128 * 2);  // [Q1 | R1]
  bf16* QR2 = (bf16*)alloc((size_t)N * 128 * 2);  // [Q2 | R2]

  // dead-before-use aliases (consumed in CSR build, before QR1/H are written)
  int* hist   = (int*)QR1;  // 2*NB*NBLK ints (~1.2 MB <= 25.6 MB)
  int* packed = (int*)H;    // 2*E ints (12.8 MB <= 76.8 MB)

  hipMemsetAsync(d_ws, 0, 256, stream);

  int gN = (N + 255) / 256;
  int gW = (N + 3) / 4;      // wave-per-node kernels: 4 waves/block
  int gF = (N + 63) / 64;

  int NB   = (N + 127) >> 7;
  int NBLK = (E + EBLK - 1) / EBLK;
  int lenH = 2 * NB * NBLK;
  int g0 = (lenH + 255) / 256;
  int g1 = (g0 + 255) / 256;

  // dtype canonicalization (sampled sniff: 1M elements, 1 atomic/block)
  int nSniff = NX < (1 << 20) ? NX : (1 << 20);
  k_sniff<<<256, 256, 0, stream>>>((const unsigned short*)x, nSniff, cnt);
  int n4 = NX / 4;
  k_convert_x<<<(n4 + 255) / 256, 256, 0, stream>>>(x, xb, cnt, n4);
  k_convert_w<<<98, 256, 0, stream>>>(d_in[2], d_in[4], d_in[6], d_in[8], d_in[10], d_in[12],
                                      d_in[3], d_in[5], d_in[7], d_in[9], d_in[11], d_in[13],
                                      wt, bsum, cnt);

  // CSR build: histogram -> scan -> bucket scatter -> per-bucket sort (no global atomics)
  k_hist<<<NBLK, 256, 0, stream>>>(row, col, hist, E, NB, NBLK);
  k_scan_block<<<g0, 256, 0, stream>>>(hist, hist, p1, lenH);
  k_scan_block<<<g1, 256, 0, stream>>>(p1, p1, p2, g0);
  k_scan_part<<<1, 1024, 0, stream>>>(p2, g1);
  k_scan_add<<<g1, 256, 0, stream>>>(p1, p2, g0);
  k_scan_add<<<g0, 256, 0, stream>>>(hist, p1, lenH);
  k_bucket_scatter<<<NBLK, 256, 0, stream>>>(row, col, hist, packed, E, NB, NBLK);
  k_bucket_csr<<<2 * NB, 256, 0, stream>>>(hist, packed, adj, deg2, roff, coff,
                                           N, NB, NBLK, 2 * E);
  k_m4scales<<<gN, 256, 0, stream>>>(roff, coff, deg2, adj, sclG1, sclG2, N);

  // fused first-order (A+B, side-interleaved) and second-order (C+D) passes
  k_passAB<<<2 * gW, 256, 0, stream>>>(roff, coff, deg2, adj, xb, sclG1, sclG2,
                                       H, QR1, QR2, N, gW);
  k_passCD<<<2 * gW, 256, 0, stream>>>(roff, coff, deg2, adj, QR1, QR2, sclG1, sclG2,
                                       H, N, gW);

  // out = 0.75 * (H @ Wcat + bsum)
  k_final<<<gF, 256, 0, stream>>>(H, wt, bsum, d_out, cnt, N);
}